// Round 2
// baseline (71.960 us; speedup 1.0000x reference)
//
#include <hip/hip_runtime.h>

#define GN   192
#define GNN  (GN * GN)
#define GTOT (GN * GN * GN)     // 7,077,888
#define L    4                  // cells per thread along k
#define RPL  (GN / L)           // 48 runs per k-line
#define NTHREADS (GTOT / L)     // 1,769,472
#define NBLOCKS  (NTHREADS / 256)  // 6912
#define NSLOTS 256

// Load 12 consecutive floats (3 cells' worth of a vector field or 12 scalars)
// from a 16B-aligned base into a statically-indexed float[12].
#define LOAD12(dst, ptr) do {                              \
    const float4* _q = (const float4*)(ptr);               \
    float4 _t0 = _q[0], _t1 = _q[1], _t2 = _q[2];          \
    dst[0]=_t0.x; dst[1]=_t0.y; dst[2]=_t0.z; dst[3]=_t0.w;\
    dst[4]=_t1.x; dst[5]=_t1.y; dst[6]=_t1.z; dst[7]=_t1.w;\
    dst[8]=_t2.x; dst[9]=_t2.y; dst[10]=_t2.z; dst[11]=_t2.w; } while (0)

__global__ __launch_bounds__(256) void ns_loss_kernel(
    const float* __restrict__ u,      // (N,N,N,3)
    const float* __restrict__ uprev,  // (N,N,N,3)
    const float* __restrict__ p,      // (N,N,N)
    const float* __restrict__ rho,    // (N,N,N)
    const float* __restrict__ nu,     // (1,)
    const float* __restrict__ h,      // (3,)
    const float* __restrict__ dt,     // (1,)
    const float* __restrict__ grav,   // (3,)
    double* __restrict__ acc)
{
    const int r    = blockIdx.x * 256 + threadIdx.x;   // run index < NTHREADS
    const int kc   = r % RPL;
    const int line = r / RPL;
    const int j    = line % GN;
    const int i    = line / GN;
    const int idx0 = line * GN + kc * L;               // first cell of the run

    // uniform scalars
    const float h0 = h[0], h1 = h[1], h2 = h[2];
    const float i2h0 = 0.5f / h0, i2h1 = 0.5f / h1, i2h2 = 0.5f / h2;
    const float ihs0 = 1.0f / (h0 * h0), ihs1 = 1.0f / (h1 * h1), ihs2 = 1.0f / (h2 * h2);
    const float invdt = 1.0f / dt[0];
    const float nu0 = nu[0];
    const float g0 = grav[0], g1 = grav[1], g2 = grav[2];

    // periodic neighbor run bases (cell indices)
    const int ipb = (i == GN - 1) ? idx0 - (GN - 1) * GNN : idx0 + GNN;
    const int imb = (i == 0)      ? idx0 + (GN - 1) * GNN : idx0 - GNN;
    const int jpb = (j == GN - 1) ? idx0 - (GN - 1) * GN  : idx0 + GN;
    const int jmb = (j == 0)      ? idx0 + (GN - 1) * GN  : idx0 - GN;
    // k halo cells (wrap only at line ends; runs are aligned so only kc==0 / kc==RPL-1 wrap)
    const int km0 = (kc == 0)       ? idx0 + (GN - 1)     : idx0 - 1;
    const int kp3 = (kc == RPL - 1) ? idx0 + L - GN       : idx0 + L;   // idx0+3-(GN-1) : idx0+4

    // ---- loads ----
    // center u, cells -1..L (halo-extended): cc[0..2]=k-1, cc[3..14]=run, cc[15..17]=k+L
    float cc[18];
    { const float* qm = u + 3 * km0; cc[0] = qm[0]; cc[1] = qm[1]; cc[2] = qm[2]; }
    { float tmp[12]; LOAD12(tmp, u + 3 * idx0);
      #pragma unroll
      for (int t = 0; t < 12; ++t) cc[3 + t] = tmp[t]; }
    { const float* qp = u + 3 * kp3; cc[15] = qp[0]; cc[16] = qp[1]; cc[17] = qp[2]; }

    float xp[12], xm[12], yp[12], ym[12], upv[12];
    LOAD12(xp, u + 3 * ipb);
    LOAD12(xm, u + 3 * imb);
    LOAD12(yp, u + 3 * jpb);
    LOAD12(ym, u + 3 * jmb);
    LOAD12(upv, uprev + 3 * idx0);

    // pressure: pa[0]=k-1, pa[1..4]=run, pa[5]=k+L
    float pa[6];
    pa[0] = p[km0];
    { float4 t = *(const float4*)(p + idx0); pa[1] = t.x; pa[2] = t.y; pa[3] = t.z; pa[4] = t.w; }
    pa[5] = p[kp3];
    float pxp[4], pxm[4], pyp[4], pym[4], rr[4];
    { float4 t = *(const float4*)(p + ipb); pxp[0]=t.x; pxp[1]=t.y; pxp[2]=t.z; pxp[3]=t.w; }
    { float4 t = *(const float4*)(p + imb); pxm[0]=t.x; pxm[1]=t.y; pxm[2]=t.z; pxm[3]=t.w; }
    { float4 t = *(const float4*)(p + jpb); pyp[0]=t.x; pyp[1]=t.y; pyp[2]=t.z; pyp[3]=t.w; }
    { float4 t = *(const float4*)(p + jmb); pym[0]=t.x; pym[1]=t.y; pym[2]=t.z; pym[3]=t.w; }
    { float4 t = *(const float4*)(rho + idx0); rr[0]=t.x; rr[1]=t.y; rr[2]=t.z; rr[3]=t.w; }

    double mom = 0.0, cont = 0.0;

    #pragma unroll
    for (int c = 0; c < L; ++c) {
        const int b = 3 * c;
        const float ucx = cc[3 + b], ucy = cc[4 + b], ucz = cc[5 + b];
        const float zmx = cc[b],     zmy = cc[1 + b], zmz = cc[2 + b];
        const float zpx = cc[6 + b], zpy = cc[7 + b], zpz = cc[8 + b];
        const float xpx = xp[b], xpy = xp[b + 1], xpz = xp[b + 2];
        const float xmx = xm[b], xmy = xm[b + 1], xmz = xm[b + 2];
        const float ypx = yp[b], ypy = yp[b + 1], ypz = yp[b + 2];
        const float ymx = ym[b], ymy = ym[b + 1], ymz = ym[b + 2];

        const float dXx = (xpx - xmx) * i2h0, dXy = (xpy - xmy) * i2h0, dXz = (xpz - xmz) * i2h0;
        const float dYx = (ypx - ymx) * i2h1, dYy = (ypy - ymy) * i2h1, dYz = (ypz - ymz) * i2h1;
        const float dZx = (zpx - zmx) * i2h2, dZy = (zpy - zmy) * i2h2, dZz = (zpz - zmz) * i2h2;

        const float lapx = (xpx - 2.0f * ucx + xmx) * ihs0 + (ypx - 2.0f * ucx + ymx) * ihs1 + (zpx - 2.0f * ucx + zmx) * ihs2;
        const float lapy = (xpy - 2.0f * ucy + xmy) * ihs0 + (ypy - 2.0f * ucy + ymy) * ihs1 + (zpy - 2.0f * ucy + zmy) * ihs2;
        const float lapz = (xpz - 2.0f * ucz + xmz) * ihs0 + (ypz - 2.0f * ucz + ymz) * ihs1 + (zpz - 2.0f * ucz + zmz) * ihs2;

        const float convx = ucx * dXx + ucy * dYx + ucz * dZx;
        const float convy = ucx * dXy + ucy * dYy + ucz * dZy;
        const float convz = ucx * dXz + ucy * dYz + ucz * dZz;

        const float dpx = (pxp[c] - pxm[c]) * i2h0;
        const float dpy = (pyp[c] - pym[c]) * i2h1;
        const float dpz = (pa[c + 2] - pa[c]) * i2h2;

        const float inv_rho = 1.0f / (rr[c] + 1e-8f);

        const float dudtx = (ucx - upv[b])     * invdt;
        const float dudty = (ucy - upv[b + 1]) * invdt;
        const float dudtz = (ucz - upv[b + 2]) * invdt;

        const float Rx = dudtx + convx + dpx * inv_rho - nu0 * lapx - g0;
        const float Ry = dudty + convy + dpy * inv_rho - nu0 * lapy - g1;
        const float Rz = dudtz + convz + dpz * inv_rho - nu0 * lapz - g2;
        const float Rc = dXx + dYy + dZz;

        mom  += (double)(Rx * Rx + Ry * Ry + Rz * Rz);
        cont += (double)(Rc * Rc);
    }

    // wave(64) reduce
    #pragma unroll
    for (int off = 32; off > 0; off >>= 1) {
        mom  += __shfl_down(mom, off);
        cont += __shfl_down(cont, off);
    }

    __shared__ double smom[4], scont[4];
    const int wid = threadIdx.x >> 6;
    const int lane = threadIdx.x & 63;
    if (lane == 0) { smom[wid] = mom; scont[wid] = cont; }
    __syncthreads();
    if (threadIdx.x == 0) {
        const double m = smom[0] + smom[1] + smom[2] + smom[3];
        const double c = scont[0] + scont[1] + scont[2] + scont[3];
        double* slot = acc + 2 * (blockIdx.x & (NSLOTS - 1));
        unsafeAtomicAdd(slot, m);
        unsafeAtomicAdd(slot + 1, c);
    }
}

__global__ __launch_bounds__(256) void ns_finalize_kernel(const double* __restrict__ acc,
                                                          float* __restrict__ out)
{
    const int tid = threadIdx.x;
    double mom = acc[2 * tid];
    double cont = acc[2 * tid + 1];
    #pragma unroll
    for (int off = 32; off > 0; off >>= 1) {
        mom  += __shfl_down(mom, off);
        cont += __shfl_down(cont, off);
    }
    __shared__ double smom[4], scont[4];
    const int wid = tid >> 6;
    const int lane = tid & 63;
    if (lane == 0) { smom[wid] = mom; scont[wid] = cont; }
    __syncthreads();
    if (tid == 0) {
        const double m = (smom[0] + smom[1] + smom[2] + smom[3]) / (double)GTOT;
        const double c = (scont[0] + scont[1] + scont[2] + scont[3]) / (double)GTOT;
        out[0] = (float)(m + 10.0 * c);
        out[1] = (float)m;
        out[2] = (float)c;
    }
}

extern "C" void kernel_launch(void* const* d_in, const int* in_sizes, int n_in,
                              void* d_out, int out_size, void* d_ws, size_t ws_size,
                              hipStream_t stream)
{
    const float* u     = (const float*)d_in[0];
    const float* uprev = (const float*)d_in[1];
    const float* p     = (const float*)d_in[2];
    const float* rho   = (const float*)d_in[3];
    const float* nu    = (const float*)d_in[4];
    const float* h     = (const float*)d_in[5];
    const float* dt    = (const float*)d_in[6];
    const float* grav  = (const float*)d_in[7];

    double* acc = (double*)d_ws;

    hipMemsetAsync(d_ws, 0, NSLOTS * 2 * sizeof(double), stream);

    ns_loss_kernel<<<NBLOCKS, 256, 0, stream>>>(u, uprev, p, rho, nu, h, dt, grav, acc);
    ns_finalize_kernel<<<1, 256, 0, stream>>>(acc, (float*)d_out);
}

// Round 3
// 70.108 us; speedup vs baseline: 1.0264x; 1.0264x over previous
//
#include <hip/hip_runtime.h>

#define GN   192
#define GNN  (GN * GN)
#define GTOT (GN * GN * GN)     // 7,077,888
#define NBLK (GN * GN)          // 36,864 blocks, one k-line each
#define CHUNK (NBLK / 8)        // 4608 — XCD chunk (36864 % 8 == 0, bijective)
#define NSLOTS 256

__global__ __launch_bounds__(192) void ns_loss_kernel(
    const float* __restrict__ u,      // (N,N,N,3)
    const float* __restrict__ uprev,  // (N,N,N,3)
    const float* __restrict__ p,      // (N,N,N)
    const float* __restrict__ rho,    // (N,N,N)
    const float* __restrict__ nu,     // (1,)
    const float* __restrict__ h,      // (3,)
    const float* __restrict__ dt,     // (1,)
    const float* __restrict__ grav,   // (3,)
    double* __restrict__ acc)
{
    // LDS staging: 5 u-lines (center, i-1, i+1, j-1, j+1), 5 p-lines, 1 uprev-line
    __shared__ float su[5][3 * GN];   // [0]=center [1]=i-1 [2]=i+1 [3]=j-1 [4]=j+1
    __shared__ float sp[5][GN];
    __shared__ float sup[3 * GN];

    const int t = threadIdx.x;        // k = t, 0..191
    const int d = blockIdx.x;
    const int o = (d & 7) * CHUNK + (d >> 3);   // XCD-chunked swizzle (bijective)
    const int i = o / GN;
    const int j = o % GN;

    const int ipr = (i == GN - 1) ? 0 : i + 1;
    const int imr = (i == 0) ? GN - 1 : i - 1;
    const int jpr = (j == GN - 1) ? 0 : j + 1;
    const int jmr = (j == 0) ? GN - 1 : j - 1;

    const int c0  = (i * GN + j) * GN;      // center line base cell index
    const int imb = (imr * GN + j) * GN;
    const int ipb = (ipr * GN + j) * GN;
    const int jmb = (i * GN + jmr) * GN;
    const int jpb = (i * GN + jpr) * GN;

    // ---- cooperative staging: all loads unit-stride across the block ----
    const float* gs[5] = { u + 3 * c0, u + 3 * imb, u + 3 * ipb, u + 3 * jmb, u + 3 * jpb };
    #pragma unroll
    for (int l = 0; l < 5; ++l) {
        su[l][t]          = gs[l][t];
        su[l][t + GN]     = gs[l][t + GN];
        su[l][t + 2 * GN] = gs[l][t + 2 * GN];
    }
    const float* ps[5] = { p + c0, p + imb, p + ipb, p + jmb, p + jpb };
    #pragma unroll
    for (int l = 0; l < 5; ++l) sp[l][t] = ps[l][t];

    const float* gup = uprev + 3 * c0;
    sup[t]          = gup[t];
    sup[t + GN]     = gup[t + GN];
    sup[t + 2 * GN] = gup[t + 2 * GN];

    const float rrc = rho[c0 + t];          // unit stride, direct

    // uniform scalars
    const float h0 = h[0], h1 = h[1], h2 = h[2];
    const float i2h0 = 0.5f / h0, i2h1 = 0.5f / h1, i2h2 = 0.5f / h2;
    const float ihs0 = 1.0f / (h0 * h0), ihs1 = 1.0f / (h1 * h1), ihs2 = 1.0f / (h2 * h2);
    const float invdt = 1.0f / dt[0];
    const float nu0 = nu[0];
    const float g0 = grav[0], g1 = grav[1], g2 = grav[2];

    __syncthreads();

    // ---- per-cell stencil from LDS ----
    const int km = (t == 0) ? GN - 1 : t - 1;
    const int kp = (t == GN - 1) ? 0 : t + 1;

    const float ucx = su[0][3 * t],  ucy = su[0][3 * t + 1],  ucz = su[0][3 * t + 2];
    const float zmx = su[0][3 * km], zmy = su[0][3 * km + 1], zmz = su[0][3 * km + 2];
    const float zpx = su[0][3 * kp], zpy = su[0][3 * kp + 1], zpz = su[0][3 * kp + 2];
    const float xmx = su[1][3 * t],  xmy = su[1][3 * t + 1],  xmz = su[1][3 * t + 2];
    const float xpx = su[2][3 * t],  xpy = su[2][3 * t + 1],  xpz = su[2][3 * t + 2];
    const float ymx = su[3][3 * t],  ymy = su[3][3 * t + 1],  ymz = su[3][3 * t + 2];
    const float ypx = su[4][3 * t],  ypy = su[4][3 * t + 1],  ypz = su[4][3 * t + 2];

    const float dXx = (xpx - xmx) * i2h0, dXy = (xpy - xmy) * i2h0, dXz = (xpz - xmz) * i2h0;
    const float dYx = (ypx - ymx) * i2h1, dYy = (ypy - ymy) * i2h1, dYz = (ypz - ymz) * i2h1;
    const float dZx = (zpx - zmx) * i2h2, dZy = (zpy - zmy) * i2h2, dZz = (zpz - zmz) * i2h2;

    const float lapx = (xpx - 2.0f * ucx + xmx) * ihs0 + (ypx - 2.0f * ucx + ymx) * ihs1 + (zpx - 2.0f * ucx + zmx) * ihs2;
    const float lapy = (xpy - 2.0f * ucy + xmy) * ihs0 + (ypy - 2.0f * ucy + ymy) * ihs1 + (zpy - 2.0f * ucy + zmy) * ihs2;
    const float lapz = (xpz - 2.0f * ucz + xmz) * ihs0 + (ypz - 2.0f * ucz + ymz) * ihs1 + (zpz - 2.0f * ucz + zmz) * ihs2;

    const float convx = ucx * dXx + ucy * dYx + ucz * dZx;
    const float convy = ucx * dXy + ucy * dYy + ucz * dZy;
    const float convz = ucx * dXz + ucy * dYz + ucz * dZz;

    const float dpx = (sp[2][t]  - sp[1][t])  * i2h0;
    const float dpy = (sp[4][t]  - sp[3][t])  * i2h1;
    const float dpz = (sp[0][kp] - sp[0][km]) * i2h2;

    const float inv_rho = 1.0f / (rrc + 1e-8f);

    const float dudtx = (ucx - sup[3 * t])     * invdt;
    const float dudty = (ucy - sup[3 * t + 1]) * invdt;
    const float dudtz = (ucz - sup[3 * t + 2]) * invdt;

    const float Rx = dudtx + convx + dpx * inv_rho - nu0 * lapx - g0;
    const float Ry = dudty + convy + dpy * inv_rho - nu0 * lapy - g1;
    const float Rz = dudtz + convz + dpz * inv_rho - nu0 * lapz - g2;
    const float Rc = dXx + dYy + dZz;

    double mom  = (double)Rx * Rx + (double)Ry * Ry + (double)Rz * Rz;
    double cont = (double)Rc * Rc;

    // ---- reduce: wave(64) shuffle, then 3 waves via LDS ----
    #pragma unroll
    for (int off = 32; off > 0; off >>= 1) {
        mom  += __shfl_down(mom, off);
        cont += __shfl_down(cont, off);
    }

    __shared__ double smom[3], scont[3];
    const int wid = t >> 6;
    const int lane = t & 63;
    if (lane == 0) { smom[wid] = mom; scont[wid] = cont; }
    __syncthreads();
    if (t == 0) {
        const double m = smom[0] + smom[1] + smom[2];
        const double c = scont[0] + scont[1] + scont[2];
        double* slot = acc + 2 * (blockIdx.x & (NSLOTS - 1));
        unsafeAtomicAdd(slot, m);
        unsafeAtomicAdd(slot + 1, c);
    }
}

__global__ __launch_bounds__(256) void ns_finalize_kernel(const double* __restrict__ acc,
                                                          float* __restrict__ out)
{
    const int tid = threadIdx.x;
    double mom = acc[2 * tid];
    double cont = acc[2 * tid + 1];
    #pragma unroll
    for (int off = 32; off > 0; off >>= 1) {
        mom  += __shfl_down(mom, off);
        cont += __shfl_down(cont, off);
    }
    __shared__ double smom[4], scont[4];
    const int wid = tid >> 6;
    const int lane = tid & 63;
    if (lane == 0) { smom[wid] = mom; scont[wid] = cont; }
    __syncthreads();
    if (tid == 0) {
        const double m = (smom[0] + smom[1] + smom[2] + smom[3]) / (double)GTOT;
        const double c = (scont[0] + scont[1] + scont[2] + scont[3]) / (double)GTOT;
        out[0] = (float)(m + 10.0 * c);
        out[1] = (float)m;
        out[2] = (float)c;
    }
}

extern "C" void kernel_launch(void* const* d_in, const int* in_sizes, int n_in,
                              void* d_out, int out_size, void* d_ws, size_t ws_size,
                              hipStream_t stream)
{
    const float* u     = (const float*)d_in[0];
    const float* uprev = (const float*)d_in[1];
    const float* p     = (const float*)d_in[2];
    const float* rho   = (const float*)d_in[3];
    const float* nu    = (const float*)d_in[4];
    const float* h     = (const float*)d_in[5];
    const float* dt    = (const float*)d_in[6];
    const float* grav  = (const float*)d_in[7];

    double* acc = (double*)d_ws;

    hipMemsetAsync(d_ws, 0, NSLOTS * 2 * sizeof(double), stream);

    ns_loss_kernel<<<NBLK, 192, 0, stream>>>(u, uprev, p, rho, nu, h, dt, grav, acc);
    ns_finalize_kernel<<<1, 256, 0, stream>>>(acc, (float*)d_out);
}